// Round 3
// baseline (241.480 us; speedup 1.0000x reference)
//
#include <hip/hip_runtime.h>

// Conv2d 3x3 s1 p1 as implicit GEMM, bf16 MFMA, fp32 accumulate.
// N=32, Cin=128, H=W=56, Cout=256. M=100352, K=1152 (kh,kw outer / ci inner).
// R3: 2-wave blocks, wave tile 64co x 128m, W read direct from L2 (no lW),
//     lX-only LDS (BK=64, XOR swizzle), packed halo flags.

#define NB   32
#define CIN  128
#define HH   56
#define WWD  56
#define COUT 256
#define HWP  3136      // 56*56
#define KTOT 1152      // 9*128
#define MTOT 100352    // 32*3136

typedef __bf16 bf16x8 __attribute__((ext_vector_type(8)));
typedef float  f32x4  __attribute__((ext_vector_type(4)));
typedef unsigned short u16;
typedef u16 u16x4 __attribute__((ext_vector_type(4)));
typedef u16 u16x8 __attribute__((ext_vector_type(8)));

__device__ __forceinline__ u16 f2b(float f) {
  unsigned u = __float_as_uint(f);
  u += 0x7fffu + ((u >> 16) & 1u);
  return (u16)(u >> 16);
}

__device__ __forceinline__ void load_lds16(const void* g, void* l) {
  __builtin_amdgcn_global_load_lds(
      (const __attribute__((address_space(1))) unsigned int*)g,
      (__attribute__((address_space(3))) unsigned int*)l, 16, 0, 0);
}

// x: [32][128][3136] f32 -> xt: [32][3136][128] bf16 (NCHW -> NHWC + cvt)
__global__ __launch_bounds__(256) void k_transpose_x(const float* __restrict__ x,
                                                     u16* __restrict__ xt) {
  __shared__ u16 tile[64][68];
  const int n  = blockIdx.z;
  const int p0 = blockIdx.x * 64;
  const int c0 = blockIdx.y * 64;
  const int t  = threadIdx.x;

  const float* xp = x + (size_t)n * CIN * HWP + (size_t)c0 * HWP + p0;
  const int pl = (t & 15) * 4;
  const int cr = t >> 4;
#pragma unroll
  for (int j = 0; j < 4; ++j) {
    int c = cr + j * 16;
    f32x4 v = *(const f32x4*)&xp[(size_t)c * HWP + pl];
    u16x4 h;
    h[0] = f2b(v[0]); h[1] = f2b(v[1]); h[2] = f2b(v[2]); h[3] = f2b(v[3]);
    *(u16x4*)&tile[c][pl] = h;
  }
  __syncthreads();
  u16* xo = xt + (size_t)n * HWP * CIN + (size_t)p0 * CIN + c0;
  const int ch = (t & 7) * 8;
  const int pr = t >> 3;
#pragma unroll
  for (int j = 0; j < 2; ++j) {
    int p = pr + j * 32;
    u16x8 o;
#pragma unroll
    for (int i = 0; i < 8; ++i) o[i] = tile[ch + i][p];
    *(u16x8*)&xo[(size_t)p * CIN + ch] = o;
  }
}

// w: [256][128][3][3] f32 -> Wt: [256][1152] bf16 with k = (kh*3+kw)*128 + ci
__global__ __launch_bounds__(256) void k_transform_w(const float* __restrict__ w,
                                                     u16* __restrict__ Wt,
                                                     u16* __restrict__ zb) {
  int o = blockIdx.x * 256 + threadIdx.x;
  if (o < COUT * KTOT) {
    int co  = o / KTOT;
    int rem = o - co * KTOT;
    int kk  = rem >> 7;
    int ci  = rem & 127;
    int kh  = kk / 3;
    int kw  = kk - kh * 3;
    Wt[o] = f2b(w[(((size_t)co * CIN + ci) * 3 + kh) * 3 + kw]);
  }
  if (blockIdx.x == 0 && threadIdx.x < 128) zb[threadIdx.x] = 0;
}

// Implicit-GEMM conv. Grid (784, 2), block 128 (2 waves).
// Block tile 128co x 128m; wave tile 64co x 128m. BK=64, 18 K-iters.
// A (weights) loaded direct from global (L2-hot); X staged in LDS (16 KB).
__global__ __launch_bounds__(128, 2) void k_conv_gemm(
    const u16* __restrict__ xt, const u16* __restrict__ Wt,
    const u16* __restrict__ zb, const float* __restrict__ bias,
    float* __restrict__ out) {
  __shared__ u16 lX[128 * 64];   // 16 KB, rows = m (128B), pieces XOR-swizzled

  const int tid  = threadIdx.x;
  const int wave = tid >> 6;     // 0..1
  const int lane = tid & 63;
  const int m0   = blockIdx.x * 128;
  const int co0  = blockIdx.y * 128;
  const int wco  = co0 + wave * 64;     // this wave's 64 co rows

  // staging lane map: row = chunk*8 + rsub; slot = lane&7; global piece = slot^rsub
  const int rsub = lane >> 3;
  const int pso  = ((lane & 7) ^ rsub) * 8;
  const int mbase = m0 + wave * 64 + rsub;   // chunk c -> pixel mbase + 8c

  // packed halo flags: 4 bits per chunk (oh==0, oh==55, ow==0, ow==55)
  unsigned flags = 0;
#pragma unroll
  for (int c = 0; c < 8; ++c) {
    int m  = mbase + 8 * c;
    int s  = m % HWP;
    int oh = s / WWD;
    int ow = s - oh * WWD;
    unsigned f = (unsigned)(oh == 0) | ((unsigned)(oh == HH - 1) << 1) |
                 ((unsigned)(ow == 0) << 2) | ((unsigned)(ow == WWD - 1) << 3);
    flags |= f << (4 * c);
  }

  f32x4 acc[4][8];
#pragma unroll
  for (int i = 0; i < 4; ++i)
#pragma unroll
    for (int j = 0; j < 8; ++j) acc[i][j] = (f32x4){0.f, 0.f, 0.f, 0.f};

  const int r  = lane & 15;
  const int q  = lane >> 4;
  const int r7 = r & 7;
  const u16* wrow0 = Wt + (size_t)(wco + r) * KTOT + q * 8;   // advance by 64/iter

  for (int kt = 0; kt < 18; ++kt) {
    const int ksp = kt >> 1;              // 0..8 = kh*3+kw
    const int kh  = ksp / 3;
    const int kw  = ksp - kh * 3;
    const int ci0 = (kt & 1) << 6;        // 0 or 64
    const int doff  = (kh - 1) * WWD + (kw - 1);   // pixel offset
    const unsigned imask = (unsigned)(kh == 0) | ((unsigned)(kh == 2) << 1) |
                           ((unsigned)(kw == 0) << 2) | ((unsigned)(kw == 2) << 3);

    __syncthreads();   // all waves done reading lX from previous iter
#pragma unroll
    for (int c = 0; c < 8; ++c) {         // stage X tile (16 KB total, 8 instr/wave)
      int chunk = wave * 8 + c;
      bool invalid = ((flags >> (4 * c)) & imask) != 0;
      const u16* g = invalid
          ? zb + pso
          : xt + (size_t)(mbase + 8 * c + doff) * CIN + ci0 + pso;
      load_lds16(g, &lX[chunk * 8 * 64]);
    }
    __syncthreads();   // staged data visible

#pragma unroll
    for (int kk = 0; kk < 2; ++kk) {
      const u16* wp = wrow0 + kt * 64 + kk * 32;
      bf16x8 a[4];
#pragma unroll
      for (int ti = 0; ti < 4; ++ti)
        a[ti] = *(const bf16x8*)(wp + (size_t)ti * 16 * KTOT);   // direct from L2
      bf16x8 b[8];
      const int sw = ((kk * 4 + q) ^ r7) * 8;
#pragma unroll
      for (int tj = 0; tj < 8; ++tj)
        b[tj] = *(const bf16x8*)(&lX[(tj * 16 + r) * 64 + sw]);
#pragma unroll
      for (int ti = 0; ti < 4; ++ti)
#pragma unroll
        for (int tj = 0; tj < 8; ++tj)
          acc[ti][tj] =
              __builtin_amdgcn_mfma_f32_16x16x32_bf16(a[ti], b[tj], acc[ti][tj], 0, 0, 0);
    }
  }

  // Epilogue: C/D layout col=lane&15 (m), row=q*4+reg (co). Add bias, store f32.
#pragma unroll
  for (int tj = 0; tj < 8; ++tj) {
    int m = m0 + tj * 16 + r;
    int n = m / HWP;
    int s = m - n * HWP;
#pragma unroll
    for (int ti = 0; ti < 4; ++ti) {
      f32x4 v = acc[ti][tj];
#pragma unroll
      for (int e = 0; e < 4; ++e) {
        int co = wco + ti * 16 + q * 4 + e;
        out[((size_t)n * COUT + co) * HWP + s] = v[e] + bias[co];
      }
    }
  }
}

extern "C" void kernel_launch(void* const* d_in, const int* in_sizes, int n_in,
                              void* d_out, int out_size, void* d_ws, size_t ws_size,
                              hipStream_t stream) {
  const float* x    = (const float*)d_in[0];
  const float* w    = (const float*)d_in[1];
  const float* bias = (const float*)d_in[2];
  float* out        = (float*)d_out;

  u16* xt = (u16*)d_ws;                       // 12,845,056 bf16 = 25.7 MB
  u16* Wt = xt + (size_t)NB * HWP * CIN;      // 294,912 bf16
  u16* zb = Wt + (size_t)COUT * KTOT;         // 128 bf16 zero page

  k_transform_w<<<dim3(1152), dim3(256), 0, stream>>>(w, Wt, zb);
  k_transpose_x<<<dim3(49, 2, 32), dim3(256), 0, stream>>>(x, xt);
  k_conv_gemm<<<dim3(784, 2), dim3(128), 0, stream>>>(xt, Wt, zb, bias, out);
}

// Round 4
// 211.413 us; speedup vs baseline: 1.1422x; 1.1422x over previous
//
#include <hip/hip_runtime.h>

// Conv2d 3x3 s1 p1 as implicit GEMM, bf16 MFMA, fp32 accumulate.
// N=32, Cin=128, H=W=56, Cout=256. M=100352, K=1152 (kh,kw outer / ci inner).
// R4: R2 GEMM structure (4 waves, 128x128, BK=64, XOR swizzle, dual LDS tiles)
//     + flag-based halo staging (VALU diet) + XCD-pair swizzle (1D grid)
//     + transpose with b32 pair reads (conflict diet).

#define NB   32
#define CIN  128
#define HH   56
#define WWD  56
#define COUT 256
#define HWP  3136      // 56*56
#define KTOT 1152      // 9*128
#define MTOT 100352    // 32*3136

typedef __bf16 bf16x8 __attribute__((ext_vector_type(8)));
typedef float  f32x4  __attribute__((ext_vector_type(4)));
typedef unsigned short u16;
typedef u16 u16x4 __attribute__((ext_vector_type(4)));
typedef u16 u16x8 __attribute__((ext_vector_type(8)));

__device__ __forceinline__ u16 f2b(float f) {
  unsigned u = __float_as_uint(f);
  u += 0x7fffu + ((u >> 16) & 1u);
  return (u16)(u >> 16);
}

__device__ __forceinline__ void load_lds16(const void* g, void* l) {
  __builtin_amdgcn_global_load_lds(
      (const __attribute__((address_space(1))) unsigned int*)g,
      (__attribute__((address_space(3))) unsigned int*)l, 16, 0, 0);
}

// x: [32][128][3136] f32 -> xt: [32][3136][128] bf16 (NCHW -> NHWC + cvt)
// Phase 1: f32x4 coalesced reads, u16x4 (b64) LDS writes into [c][p] tile.
// Phase 2: per thread 8x b32 reads (two p columns at once), 2x 16B global stores.
__global__ __launch_bounds__(256) void k_transpose_x(const float* __restrict__ x,
                                                     u16* __restrict__ xt) {
  __shared__ u16 tile[64 * 68];   // [c][p], row stride 68 u16 = 136B (b64-aligned)
  const int n  = blockIdx.z;
  const int p0 = blockIdx.x * 64;
  const int c0 = blockIdx.y * 64;
  const int t  = threadIdx.x;

  const float* xp = x + (size_t)n * CIN * HWP + (size_t)c0 * HWP + p0;
  const int pl = (t & 15) * 4;
  const int cr = t >> 4;
#pragma unroll
  for (int j = 0; j < 4; ++j) {
    int c = cr + j * 16;
    f32x4 v = *(const f32x4*)&xp[(size_t)c * HWP + pl];
    u16x4 h;
    h[0] = f2b(v[0]); h[1] = f2b(v[1]); h[2] = f2b(v[2]); h[3] = f2b(v[3]);
    *(u16x4*)&tile[c * 68 + pl] = h;
  }
  __syncthreads();
  u16* xo = xt + (size_t)n * HWP * CIN + (size_t)p0 * CIN + c0;
  const int ch = (t & 7) * 8;       // channel chunk (8 consecutive c)
  const int p2 = (t >> 3) * 2;      // even pixel; thread handles p2, p2+1
  u16x8 o0, o1;
#pragma unroll
  for (int i = 0; i < 8; ++i) {
    unsigned pair = *(const unsigned*)&tile[(ch + i) * 68 + p2];  // b32: p2,p2+1
    o0[i] = (u16)(pair & 0xffffu);
    o1[i] = (u16)(pair >> 16);
  }
  *(u16x8*)&xo[(size_t)p2 * CIN + ch] = o0;
  *(u16x8*)&xo[(size_t)(p2 + 1) * CIN + ch] = o1;
}

// w: [256][128][3][3] f32 -> Wt: [256][1152] bf16 with k = (kh*3+kw)*128 + ci
__global__ __launch_bounds__(256) void k_transform_w(const float* __restrict__ w,
                                                     u16* __restrict__ Wt,
                                                     u16* __restrict__ zb) {
  int o = blockIdx.x * 256 + threadIdx.x;
  if (o < COUT * KTOT) {
    int co  = o / KTOT;
    int rem = o - co * KTOT;
    int kk  = rem >> 7;
    int ci  = rem & 127;
    int kh  = kk / 3;
    int kw  = kk - kh * 3;
    Wt[o] = f2b(w[(((size_t)co * CIN + ci) * 3 + kh) * 3 + kw]);
  }
  if (blockIdx.x == 0 && threadIdx.x < 128) zb[threadIdx.x] = 0;
}

// Implicit-GEMM conv. 1D grid 1568 blocks, XCD-pair swizzled; block 256 (4 waves).
// 128x128 tile, BK=64, 18 K-iters, XOR piece-swizzled LDS (conflict-free b128).
__global__ __launch_bounds__(256, 4) void k_conv_gemm(
    const u16* __restrict__ xt, const u16* __restrict__ Wt,
    const u16* __restrict__ zb, const float* __restrict__ bias,
    float* __restrict__ out) {
  __shared__ u16 lW[128 * 64];   // 16 KB
  __shared__ u16 lX[128 * 64];   // 16 KB

  const int tid  = threadIdx.x;
  const int wave = tid >> 6;
  const int lane = tid & 63;
  // XCD-pair swizzle: ids k and k+8 share id%8 (same XCD) and map to the same
  // m-tile with co-half 0/1 -> xt tile fetched once per XCD L2.
  const int id  = blockIdx.x;
  const int m0  = (((id >> 4) << 3) | (id & 7)) * 128;
  const int co0 = ((id >> 3) & 1) * 128;

  const int wrow = (wave >> 1) * 64;   // co offset of this wave's 64x64
  const int wcol = (wave & 1) * 64;    // m offset

  // staging lane map: row = chunk*8 + rsub; slot = lane&7; global piece = slot^rsub
  const int rsub = lane >> 3;
  const int pso  = ((lane & 7) ^ rsub) * 8;

  // Loop-invariant staging bases + per-row halo flags (4 bits per chunk).
  const u16* bx[4];
  const u16* bw[4];
  unsigned flags = 0;
#pragma unroll
  for (int c = 0; c < 4; ++c) {
    int m  = m0 + (wave * 4 + c) * 8 + rsub;   // xt pixel index == m
    int s  = m % HWP;
    int oh = s / WWD;
    int ow = s - oh * WWD;
    unsigned f = (unsigned)(oh == 0) | ((unsigned)(oh == HH - 1) << 1) |
                 ((unsigned)(ow == 0) << 2) | ((unsigned)(ow == WWD - 1) << 3);
    flags |= f << (4 * c);
    bx[c] = xt + (size_t)m * CIN + pso;
    bw[c] = Wt + (size_t)(co0 + wave * 32 + c * 8 + rsub) * KTOT + pso;
  }
  const u16* zp = zb + pso;

  f32x4 acc[4][4];
#pragma unroll
  for (int i = 0; i < 4; ++i)
#pragma unroll
    for (int j = 0; j < 4; ++j) acc[i][j] = (f32x4){0.f, 0.f, 0.f, 0.f};

  const int r  = lane & 15;
  const int q  = lane >> 4;
  const int r7 = r & 7;

  for (int kt = 0; kt < 18; ++kt) {
    const int ksp = kt >> 1;              // 0..8 = kh*3+kw (uniform -> SALU)
    const int kh  = ksp / 3;
    const int kw  = ksp - kh * 3;
    const int koff = ((kh - 1) * WWD + (kw - 1)) * CIN + ((kt & 1) << 6);
    const unsigned imask = (unsigned)(kh == 0) | ((unsigned)(kh == 2) << 1) |
                           ((unsigned)(kw == 0) << 2) | ((unsigned)(kw == 2) << 3);

    __syncthreads();   // all waves done reading LDS from previous iter
#pragma unroll
    for (int c = 0; c < 4; ++c) {         // stage W tile (16 KB)
      int rowW = wave * 32 + c * 8;
      load_lds16(bw[c] + kt * 64, &lW[rowW * 64]);
    }
#pragma unroll
    for (int c = 0; c < 4; ++c) {         // stage X tile (16 KB), halo -> zero page
      bool invalid = ((flags >> (4 * c)) & imask) != 0;
      const u16* g = invalid ? zp : (bx[c] + koff);
      load_lds16(g, &lX[(wave * 32 + c * 8) * 64]);
    }
    __syncthreads();   // staged data visible

#pragma unroll
    for (int kk = 0; kk < 2; ++kk) {
      bf16x8 a[4], b[4];
      const int sw = ((kk * 4 + q) ^ r7) * 8;   // swizzled segment offset
#pragma unroll
      for (int ti = 0; ti < 4; ++ti)
        a[ti] = *(const bf16x8*)(&lW[(wrow + ti * 16 + r) * 64 + sw]);
#pragma unroll
      for (int tj = 0; tj < 4; ++tj)
        b[tj] = *(const bf16x8*)(&lX[(wcol + tj * 16 + r) * 64 + sw]);
#pragma unroll
      for (int ti = 0; ti < 4; ++ti)
#pragma unroll
        for (int tj = 0; tj < 4; ++tj)
          acc[ti][tj] =
              __builtin_amdgcn_mfma_f32_16x16x32_bf16(a[ti], b[tj], acc[ti][tj], 0, 0, 0);
    }
  }

  // Epilogue: C/D layout col=lane&15 (m), row=q*4+reg (co). Add bias, store f32.
#pragma unroll
  for (int tj = 0; tj < 4; ++tj) {
    int m = m0 + wcol + tj * 16 + r;
    int n = m / HWP;
    int s = m - n * HWP;
#pragma unroll
    for (int ti = 0; ti < 4; ++ti) {
      f32x4 v = acc[ti][tj];
#pragma unroll
      for (int e = 0; e < 4; ++e) {
        int co = co0 + wrow + ti * 16 + q * 4 + e;
        out[((size_t)n * COUT + co) * HWP + s] = v[e] + bias[co];
      }
    }
  }
}

extern "C" void kernel_launch(void* const* d_in, const int* in_sizes, int n_in,
                              void* d_out, int out_size, void* d_ws, size_t ws_size,
                              hipStream_t stream) {
  const float* x    = (const float*)d_in[0];
  const float* w    = (const float*)d_in[1];
  const float* bias = (const float*)d_in[2];
  float* out        = (float*)d_out;

  u16* xt = (u16*)d_ws;                       // 12,845,056 bf16 = 25.7 MB
  u16* Wt = xt + (size_t)NB * HWP * CIN;      // 294,912 bf16
  u16* zb = Wt + (size_t)COUT * KTOT;         // 128 bf16 zero page

  k_transform_w<<<dim3(1152), dim3(256), 0, stream>>>(w, Wt, zb);
  k_transpose_x<<<dim3(49, 2, 32), dim3(256), 0, stream>>>(x, xt);
  k_conv_gemm<<<dim3(1568), dim3(256), 0, stream>>>(xt, Wt, zb, bias, out);
}